// Round 11
// baseline (483.262 us; speedup 1.0000x reference)
//
#include <hip/hip_runtime.h>
#include <hip/hip_bf16.h>

#define BB 2
#define SS 2048
#define HH 2048
#define NH 16
#define NKV 4
#define DD 128
#define EE 2
#define MTOK (BB*SS)      // 4096
#define NQ (NH*DD)        // 2048
#define NKVD (NKV*DD)     // 512
#define SC2 (0.08838834764831845f * 1.4426950408889634f)  // SCALE * log2(e)

typedef __bf16 bf16_t;
typedef __bf16 bf16x8 __attribute__((ext_vector_type(8)));
typedef __bf16 bf16x4 __attribute__((ext_vector_type(4)));
typedef __bf16 bf16x2 __attribute__((ext_vector_type(2)));
typedef float  f32x4  __attribute__((ext_vector_type(4)));

#define MFMA16(a,b,c) __builtin_amdgcn_mfma_f32_16x16x32_bf16(a,b,c,0,0,0)

// global -> LDS direct (width 16). LDS dest is wave-uniform + lane*16; the
// swizzle goes on the GLOBAL source (rule 21) and on the LDS *read* side.
#define GLDS16(g, l) __builtin_amdgcn_global_load_lds( \
    (__attribute__((address_space(1))) void*)(g), \
    (__attribute__((address_space(3))) void*)(l), 16, 0, 0)

// ---------------- cast / transpose-cast ----------------

__global__ void k_cast(const float* __restrict__ x, bf16_t* __restrict__ y, int n4){
  int i = blockIdx.x*256 + threadIdx.x;
  if (i >= n4) return;
  float4 v = ((const float4*)x)[i];
  bf16x4 o;
  o[0]=(bf16_t)v.x; o[1]=(bf16_t)v.y; o[2]=(bf16_t)v.z; o[3]=(bf16_t)v.w;
  ((bf16x4*)y)[i] = o;
}

// W (E,K,N) f32 -> Wt (E,N,K) bf16
__global__ void k_tcast(const float* __restrict__ W, bf16_t* __restrict__ Wt, int K, int N){
  __shared__ float t[32][33];
  const int e = blockIdx.z;
  const size_t base = (size_t)e*K*N;
  const int k0 = blockIdx.x*32, n0 = blockIdx.y*32;
  const int tx = threadIdx.x & 31, ty = threadIdx.x >> 5; // 256 thr: ty 0..7
  #pragma unroll
  for (int i=0;i<4;i++)
    t[ty+i*8][tx] = W[base + (size_t)(k0+ty+i*8)*N + n0+tx];
  __syncthreads();
  #pragma unroll
  for (int i=0;i<4;i++)
    Wt[base + (size_t)(n0+ty+i*8)*K + k0+tx] = (bf16_t)t[tx][ty+i*8];
}

// ---------------- expert routing: position -> token map ----------------
// Single block, 256 threads, 16 tokens each. map[0..n0) = expert-0 tokens
// (in index order), map[n0..4096) = expert-1 tokens. n0 -> *n0out.
__global__ void __launch_bounds__(256) k_route(const int* __restrict__ tt,
                                               int* __restrict__ map,
                                               int* __restrict__ n0out){
  __shared__ int s[257];
  const int t = threadIdx.x;
  int c0 = 0;
  #pragma unroll
  for (int j=0;j<16;j++) c0 += (tt[t*16+j] == 0);
  s[t] = c0;
  __syncthreads();
  if (t == 0){
    int run = 0;
    for (int i=0;i<256;i++){ int v = s[i]; s[i] = run; run += v; }
    s[256] = run;
    *n0out = run;
  }
  __syncthreads();
  const int n0 = s[256];
  int p0 = s[t];
  int p1 = n0 + t*16 - s[t];
  #pragma unroll
  for (int j=0;j<16;j++){
    int i = t*16 + j;
    if (tt[i] == 0) map[p0++] = i;
    else            map[p1++] = i;
  }
}

// ---------------- routed expert GEMM (128x128 tile, 2-phase m97 structure) --
// EPI: 0=Q(rope->qr), 1=K(rope->kr), 2=V(->vt transposed), 3=O(f32->d_out)
// M is the expert-sorted position axis: positions [0,n0) are expert 0,
// [n0,4096) expert 1. M-blocks: e0 gets mbi in [0, ceil(n0/128)); e1 gets
// M-tiles [floor(n0/128), 32). The straddle tile is covered by one block of
// each expert with disjoint row masks (p<n0 / p>=n0). Grid x = 33 (max
// ceil+count); out-of-range blocks exit. A rows gathered via map (indexed
// row base, coalesced within row); epilogue scatters to token positions.

template<int EPI, int NOUT>
__global__ void __launch_bounds__(256) k_gemmRT(
    const bf16_t* __restrict__ A,     // (MTOK, 2048) token-major
    const bf16_t* __restrict__ Wt,    // (EE, NOUT, 2048)
    const float*  __restrict__ bias,  // (EE, NOUT) or null
    const int*    __restrict__ map,   // (MTOK) position -> token
    const int*    __restrict__ n0p,   // routed count of expert 0
    const float*  __restrict__ cosp,
    const float*  __restrict__ sinp,
    void* __restrict__ outp)
{
  __shared__ __align__(128) char lds[32768];  // A rows[128][64]bf16, B cols[128][64]bf16
  const int tid = threadIdx.x;
  const int w = tid >> 6, lane = tid & 63;
  const int l4 = lane >> 4, l15 = lane & 15;

  // bijective chunked XCD swizzle over nwg = 33 * (NOUT/128)
  const int NB  = NOUT/128;
  const int nwg = 33*NB;
  const int orig = blockIdx.x + 33*blockIdx.y;
  const int qq = nwg >> 3, rr = nwg & 7;
  const int x = orig & 7, so = orig >> 3;
  const int wg = (x < rr ? x*(qq+1) : rr*(qq+1) + (x-rr)*qq) + so;
  const int mbi = wg % 33;
  const int by  = wg / 33;
  const int bcol = by * 128;

  // expert / row-range decode
  const int n0 = *n0p;
  const int c0 = (n0 + 127) >> 7;     // # expert-0 M-blocks
  const int f0 = n0 >> 7;             // first expert-1 M-tile
  int e, rstart, lo, hi;
  if (mbi < c0){
    e = 0; rstart = mbi*128; lo = rstart;
    hi = rstart+128 < n0 ? rstart+128 : n0;
  } else {
    int j = mbi - c0;
    int mb1 = f0 + j;
    if (mb1 >= 32) return;            // uniform block exit (before barriers)
    e = 1; rstart = mb1*128;
    lo = rstart > n0 ? rstart : n0;
    hi = rstart+128;
  }
  const bf16_t* Wte = Wt + (size_t)e * NOUT * HH;

  // gathered A-row bases for this thread's 4 staging rows
  int ar[4];
  #pragma unroll
  for (int i=0;i<4;i++)
    ar[i] = map[rstart + w*32 + i*8 + (lane>>3)];

  f32x4 acc[2][8] = {};

  for (int k0 = 0; k0 < HH; k0 += 64){
    #pragma unroll
    for (int i=0;i<4;i++){
      int row = w*32 + i*8 + (lane>>3);
      int gc = (lane&7) ^ (row&7);           // inverse swizzle on source
      GLDS16(A + (size_t)ar[i]*HH + k0 + gc*8, lds + (w*4+i)*1024);
    }
    #pragma unroll
    for (int i=0;i<4;i++){
      int c = w*4 + i;
      int col = c*8 + (lane>>3);
      int gc = (lane&7) ^ (col&7);
      GLDS16(Wte + (size_t)(bcol+col)*HH + k0 + gc*8, lds + 16384 + c*1024);
    }
    __syncthreads();
    #pragma unroll
    for (int ck=0;ck<2;ck++){
      const int kb = (ck*32 + l4*8)*2;
      bf16x8 a[2];
      #pragma unroll
      for (int m=0;m<2;m++){
        int row = w*32 + m*16 + l15;
        a[m] = *(const bf16x8*)(lds + row*128 + (kb ^ ((row&7)<<4)));
      }
      #pragma unroll
      for (int n=0;n<8;n++){
        int col = n*16 + l15;
        bf16x8 bf = *(const bf16x8*)(lds + 16384 + col*128 + (kb ^ ((col&7)<<4)));
        acc[0][n] = MFMA16(a[0], bf, acc[0][n]);
        acc[1][n] = MFMA16(a[1], bf, acc[1][n]);
      }
    }
    __syncthreads();
  }

  // epilogue: C/D layout col=lane&15, row=(lane>>4)*4+j; scatter via map
  #pragma unroll
  for (int m=0;m<2;m++){
    #pragma unroll
    for (int j=0;j<4;j++){
      int p = rstart + w*32 + m*16 + l4*4 + j;   // sorted position
      if (p < lo || p >= hi) continue;
      int token = map[p];
      int b = token >> 11, s = token & (SS-1);
      #pragma unroll
      for (int n=0;n<8;n++){
        int colh = n*16 + l15;
        int col  = bcol + colh;
        float v = acc[m][n][j];
        if constexpr (EPI != 3) v += bias[(size_t)e*NOUT + col];
        if constexpr (EPI == 0 || EPI == 1){
          float pv = acc[m][n^4][j] + bias[(size_t)e*NOUT + (col^64)];
          int d = colh;
          float cs = cosp[(size_t)token*DD + d];
          float sn = sinp[(size_t)token*DD + d];
          float rot = (d < 64) ? -pv : pv;
          v = v*cs + rot*sn;
          if constexpr (EPI == 0)
            ((bf16_t*)outp)[(((size_t)(b*NH + by))*SS + s)*DD + d] = (bf16_t)v;
          else
            ((bf16_t*)outp)[(((size_t)(b*NKV + by))*SS + s)*DD + d] = (bf16_t)v;
        } else if constexpr (EPI == 2){
          ((bf16_t*)outp)[(((size_t)(b*NKV + by))*DD + colh)*SS + s] = (bf16_t)v;
        } else {
          ((float*)outp)[(size_t)token*HH + col] = v;
        }
      }
    }
  }
}

// ---------------- flash attention (swapped-QK^T, in-lane softmax) ----------
// grid (16, 32 bh). Paired q-tiles (31-x, x) -> uniform 33 KV-iters.
__global__ void __launch_bounds__(256) k_attn(
    const bf16_t* __restrict__ qr,   // (B,NH,S,D)
    const bf16_t* __restrict__ kr,   // (B,NKV,S,D)
    const bf16_t* __restrict__ vt,   // (B,NKV,D,S)
    bf16_t* __restrict__ attn)       // (MTOK, NH*D)
{
  // buf c at c*32768: K [64][128]bf16 swz, V [128][64]bf16 swz; P^T at 65536 + w*2048
  __shared__ __align__(128) char lds[73728];
  const int tid = threadIdx.x, w = tid>>6, lane = tid&63;
  const int l4 = lane>>4, l15 = lane&15;
  // chunked XCD swizzle: XCD r hosts bh in [4r,4r+4) = one shared KV + 4 Q heads
  const int orig = blockIdx.x + 16*blockIdx.y;
  const int rbm = ((orig & 7) << 6) + (orig >> 3);
  const int bx = rbm & 15;
  const int bh = rbm >> 4;
  const int b = bh >> 4, h = bh & 15;
  const int kvh = h >> 2;
  const bf16_t* Kbase = kr + (size_t)(b*NKV + kvh)*SS*DD;
  const bf16_t* Vbase = vt + (size_t)(b*NKV + kvh)*DD*SS;
  const bf16_t* Qhead = qr + (size_t)(b*NH + h)*SS*DD;
  char* Pl = lds + 65536 + w*2048;

  auto stage = [&](int buf, int t){
    const int kv0 = t*64;
    char* base = lds + buf*32768;
    #pragma unroll
    for (int i=0;i<4;i++){            // K tile: chunk = 4 rows of 256B
      int c = w*4+i;
      int row = c*4 + l4;
      int gc = l15 ^ (row&7);
      GLDS16(Kbase + (size_t)(kv0 + row)*DD + gc*8, base + c*1024);
    }
    #pragma unroll
    for (int i=0;i<4;i++){            // V^T tile: chunk = 8 rows of 128B
      int c = w*4+i;
      int row = c*8 + (lane>>3);
      int gc = (lane&7) ^ (row&7);
      GLDS16(Vbase + (size_t)row*SS + kv0 + gc*8, base + 16384 + c*1024);
    }
  };

  #pragma unroll 1
  for (int qi=0; qi<2; qi++){
    const int qt = qi ? bx : (31 - bx);
    const int q0 = qt*64;
    const int nt = qt+1;
    const int qrow = w*16 + l15;           // this lane's q-row (local)

    // Q frags, with SCALE*log2e folded in (bf16)
    bf16x8 q[4];
    {
      const bf16_t* qp = Qhead + (size_t)(q0 + qrow)*DD + l4*8;
      #pragma unroll
      for (int ck=0;ck<4;ck++){
        bf16x8 tq = *(const bf16x8*)(qp + ck*32);
        #pragma unroll
        for (int u=0;u<8;u++) tq[u] = (bf16_t)((float)tq[u] * SC2);
        q[ck] = tq;
      }
    }

    f32x4 o[8] = {};
    float mreg = -3.0e38f, lreg = 0.f;

    stage(0, 0);
    __syncthreads();

    for (int t=0; t<nt; t++){
      const int cur = t & 1;
      if (t+1 < nt) stage(cur^1, t+1);      // issue-early prefetch
      char* Kl = lds + cur*32768;
      char* Vl = Kl + 16384;

      // QK^T swapped: s[n][j] = S[kv = kv0+n*16+l4*4+j][q = q0+qrow] (log2 dom)
      f32x4 s[4] = {};
      #pragma unroll
      for (int ck=0;ck<4;ck++){
        const int kb = (ck*32 + l4*8)*2;
        #pragma unroll
        for (int n=0;n<4;n++){
          int kv = n*16 + l15;
          bf16x8 kf = *(const bf16x8*)(Kl + kv*256 + (kb ^ ((kv&7)<<4)));
          s[n] = MFMA16(kf, q[ck], s[n]);
        }
      }

      // causal mask only on diag tile: kv > q
      if (t == nt-1){
        const int kv0 = t*64;
        #pragma unroll
        for (int n=0;n<4;n++){
          #pragma unroll
          for (int j=0;j<4;j++)
            if (kv0 + n*16 + l4*4 + j > q0 + qrow) s[n][j] = -1e30f;
        }
      }

      // tile max: 16 in-lane values + 2 shfl rounds (across l4 groups)
      float pm = -1e30f;
      #pragma unroll
      for (int n=0;n<4;n++){
        #pragma unroll
        for (int j=0;j<4;j++) pm = fmaxf(pm, s[n][j]);
      }
      pm = fmaxf(pm, __shfl_xor(pm, 16));
      pm = fmaxf(pm, __shfl_xor(pm, 32));

      // defer-max (log2 domain, THR=8)
      if (__any((int)(pm > mreg + 8.f))){
        float mn = fmaxf(mreg, pm);
        float al = exp2f(mreg - mn);
        mreg = mn;
        lreg *= al;
        #pragma unroll
        for (int n=0;n<8;n++){
          #pragma unroll
          for (int j=0;j<4;j++) o[n][j] *= al;
        }
      }

      // p = 2^(s-m), row-sum in-lane + 2 shfl
      float ps = 0.f;
      #pragma unroll
      for (int n=0;n<4;n++){
        #pragma unroll
        for (int j=0;j<4;j++){
          float p = exp2f(s[n][j] - mreg);
          s[n][j] = p;
          ps += p;
        }
      }
      ps += __shfl_xor(ps, 16);
      ps += __shfl_xor(ps, 32);
      lreg += ps;

      // bounce P^T to per-wave LDS: [q=16][k=64] bf16, 16B-slot swizzled by q
      #pragma unroll
      for (int n=0;n<4;n++){
        #pragma unroll
        for (int jh=0;jh<2;jh++){
          int slot = n*2 + (l4>>1);
          int phys = ((slot ^ (l15&7))<<4) + (l4&1)*8 + jh*4;
          bf16x2 pr;
          pr[0] = (bf16_t)s[n][2*jh];
          pr[1] = (bf16_t)s[n][2*jh+1];
          *(bf16x2*)(Pl + l15*128 + phys) = pr;
        }
      }

      // PV swapped: o[n] = mfma(V^T-frag, P^T-frag): D[d][q]
      #pragma unroll
      for (int ck=0;ck<2;ck++){
        int sl = ck*4 + l4;
        bf16x8 pb = *(const bf16x8*)(Pl + l15*128 + ((sl ^ (l15&7))<<4));
        int kvb = ck*64 + l4*16;
        #pragma unroll
        for (int n=0;n<8;n++){
          int d = n*16 + l15;
          bf16x8 vf = *(const bf16x8*)(Vl + d*128 + (kvb ^ ((d&7)<<4)));
          o[n] = MFMA16(vf, pb, o[n]);
        }
      }
      __syncthreads();   // drains prefetch vmcnt + protects buffers
    }

    // epilogue: lane owns q-row; o[n][j] = O[q][d = n*16+l4*4+j]
    {
      float inv = 1.f / lreg;
      int s_ = q0 + qrow;
      size_t base = (size_t)(b*SS + s_)*NQ + (size_t)h*DD;
      #pragma unroll
      for (int n=0;n<8;n++){
        bf16x4 ov;
        #pragma unroll
        for (int j=0;j<4;j++) ov[j] = (bf16_t)(o[n][j]*inv);
        *(bf16x4*)(attn + base + n*16 + l4*4) = ov;
      }
    }
  }
}

// ---------------- launch ----------------

extern "C" void kernel_launch(void* const* d_in, const int* in_sizes, int n_in,
                              void* d_out, int out_size, void* d_ws, size_t ws_size,
                              hipStream_t stream){
  const float* hs   = (const float*)d_in[0];
  const int*   tt   = (const int*)  d_in[1];
  const float* cosp = (const float*)d_in[2];
  const float* sinp = (const float*)d_in[3];
  const float* Wq   = (const float*)d_in[4];
  const float* bq   = (const float*)d_in[5];
  const float* Wk   = (const float*)d_in[6];
  const float* bk   = (const float*)d_in[7];
  const float* Wv   = (const float*)d_in[8];
  const float* bv   = (const float*)d_in[9];
  const float* Wo   = (const float*)d_in[10];
  float* out = (float*)d_out;

  if (ws_size < 100663296ull) return;

  // atb aliases hsb: hsb is dead after V-proj; attn writes atb after V-proj.
  char* wsp = (char*)d_ws;
  bf16_t* hsb = (bf16_t*)wsp;  wsp += (size_t)MTOK*HH*2;     // also atb
  bf16_t* atb = hsb;
  bf16_t* wqt = (bf16_t*)wsp;  wsp += (size_t)EE*NQ*HH*2;
  bf16_t* wkt = (bf16_t*)wsp;  wsp += (size_t)EE*NKVD*HH*2;
  bf16_t* wvt = (bf16_t*)wsp;  wsp += (size_t)EE*NKVD*HH*2;
  bf16_t* wot = (bf16_t*)wsp;  wsp += (size_t)EE*HH*NQ*2;
  bf16_t* qrb = (bf16_t*)wsp;  wsp += (size_t)BB*NH*SS*DD*2;
  bf16_t* krb = (bf16_t*)wsp;  wsp += (size_t)BB*NKV*SS*DD*2;
  bf16_t* vtb = (bf16_t*)wsp;  wsp += (size_t)BB*NKV*DD*SS*2;
  int* map  = (int*)wsp;       wsp += (size_t)MTOK*4;
  int* n0w  = (int*)wsp;       wsp += 64;

  k_cast<<<MTOK*HH/4/256, 256, 0, stream>>>(hs, hsb, MTOK*HH/4);
  k_route<<<1, 256, 0, stream>>>(tt, map, n0w);
  k_tcast<<<dim3(HH/32, NQ/32,  EE), 256, 0, stream>>>(Wq, wqt, HH, NQ);
  k_tcast<<<dim3(HH/32, NKVD/32,EE), 256, 0, stream>>>(Wk, wkt, HH, NKVD);
  k_tcast<<<dim3(HH/32, NKVD/32,EE), 256, 0, stream>>>(Wv, wvt, HH, NKVD);
  k_tcast<<<dim3(NQ/32, HH/32,  EE), 256, 0, stream>>>(Wo, wot, NQ, HH);

  k_gemmRT<0, NQ  ><<<dim3(33, NQ/128),   256, 0, stream>>>(hsb, wqt, bq, map, n0w, cosp, sinp, qrb);
  k_gemmRT<1, NKVD><<<dim3(33, NKVD/128), 256, 0, stream>>>(hsb, wkt, bk, map, n0w, cosp, sinp, krb);
  k_gemmRT<2, NKVD><<<dim3(33, NKVD/128), 256, 0, stream>>>(hsb, wvt, bv, map, n0w, cosp, sinp, vtb);

  k_attn<<<dim3(16, BB*NH), 256, 0, stream>>>(qrb, krb, vtb, atb);

  k_gemmRT<3, NQ  ><<<dim3(33, NQ/128),   256, 0, stream>>>(atb, wot, nullptr, map, n0w, cosp, sinp, out);
}